// Round 5
// baseline (641.899 us; speedup 1.0000x reference)
//
#include <hip/hip_runtime.h>
#include <cstddef>
#include <cstdint>

// Problem: B=2, S=2048, E=1024, H=16, D=64.  Softmax over HEADS (ref quirk).
#define BATCH 2
#define S_LEN 2048
#define E_DIM 1024
#define NH    16
#define HD    64
#define M_ROWS (BATCH * S_LEN)   // 4096

typedef unsigned short u16;
typedef short  bf16x8 __attribute__((ext_vector_type(8)));
typedef float  f32x4  __attribute__((ext_vector_type(4)));

__device__ __forceinline__ u16 f2bf(float f) {
    union { float f; unsigned u; } v; v.f = f;
    unsigned r = v.u + 0x7fffu + ((v.u >> 16) & 1u);   // RNE
    return (u16)(r >> 16);
}
__device__ __forceinline__ float bf2f(u16 h) {
    union { unsigned u; float f; } v; v.u = ((unsigned)h) << 16;
    return v.f;
}

// ---------------------------------------------------------------------------
// fp32 -> bf16 bulk convert (n % 4 == 0)
// ---------------------------------------------------------------------------
__global__ void cvt_bf16(const float* __restrict__ in, u16* __restrict__ out, int n)
{
    int i = (blockIdx.x * 256 + threadIdx.x) * 4;
    if (i + 3 < n) {
        float4 v = *(const float4*)(in + i);
        u16 o[4] = { f2bf(v.x), f2bf(v.y), f2bf(v.z), f2bf(v.w) };
        *(uint2*)(out + i) = *(const uint2*)o;
    }
}

// ---------------------------------------------------------------------------
// ctx = p0+p1+p2+p3 (bf16 in, fp32 add, bf16 out)
// ---------------------------------------------------------------------------
__global__ void combine4(const u16* __restrict__ p0, const u16* __restrict__ p1,
                         const u16* __restrict__ p2, const u16* __restrict__ p3,
                         u16* __restrict__ c, int n)
{
    int i = (blockIdx.x * 256 + threadIdx.x) * 4;
    if (i + 3 < n) {
        uint2 u0 = *(const uint2*)(p0 + i);
        uint2 u1 = *(const uint2*)(p1 + i);
        uint2 u2 = *(const uint2*)(p2 + i);
        uint2 u3 = *(const uint2*)(p3 + i);
        const u16* a = (const u16*)&u0; const u16* b = (const u16*)&u1;
        const u16* d = (const u16*)&u2; const u16* e = (const u16*)&u3;
        u16 o[4];
#pragma unroll
        for (int j = 0; j < 4; ++j)
            o[j] = f2bf((bf2f(a[j]) + bf2f(b[j])) + (bf2f(d[j]) + bf2f(e[j])));
        *(uint2*)(c + i) = *(const uint2*)o;
    }
}

// ---------------------------------------------------------------------------
// V [b][s][e] -> Vt [b][e][s]   (bf16). grid = 2*128 blocks, 256 thr.
// ---------------------------------------------------------------------------
__global__ void transpose_v(const u16* __restrict__ Vb, u16* __restrict__ Vt)
{
    const int t  = threadIdx.x;
    const int b  = blockIdx.x >> 7;
    const int s0 = (blockIdx.x & 127) * 16;
    const int s  = t >> 4;          // 0..15
    const int eq = t & 15;          // 0..15
    const size_t inb  = ((size_t)b * S_LEN + s0 + s) * E_DIM;
    const size_t outb = (size_t)b * E_DIM * S_LEN;
#pragma unroll
    for (int i = 0; i < 8; ++i) {
        const int e8 = i * 16 + eq;                        // 0..127
        bf16x8 v = *(const bf16x8*)(Vb + inb + e8 * 8);
        const u16* pv = (const u16*)&v;
#pragma unroll
        for (int j = 0; j < 8; ++j)
            Vt[outb + (size_t)(e8 * 8 + j) * S_LEN + s0 + s] = pv[j];
    }
}

// ---------------------------------------------------------------------------
// bf16 MFMA GEMM (NT): C[m,n] = sum_k A[m,k]*B[n,k] + bias[n]   (unchanged)
// ---------------------------------------------------------------------------
template<bool OUT_BF16>
__global__ __launch_bounds__(256, 2)
void gemm_bt(const u16* __restrict__ A, const u16* __restrict__ B,
             const float* __restrict__ bias, void* __restrict__ Cout,
             int M, int N, int K)
{
    __shared__ u16 Al[128 * 32];
    __shared__ u16 Bl[128 * 32];
    const int t    = threadIdx.x;
    const int w    = t >> 6, lane = t & 63;
    const int quad = lane >> 4, lm = lane & 15;
    const int wy   = w >> 1, wx = w & 1;
    const int m0   = blockIdx.x * 128, n0 = blockIdx.y * 128;

    f32x4 acc[4][4] = {};

    for (int kb = 0; kb < K; kb += 32) {
        bf16x8 av[2], bv[2];
#pragma unroll
        for (int i = 0; i < 2; ++i) {
            const int unit = i * 256 + t;
            const int r = unit >> 2, cu = unit & 3;
            av[i] = *(const bf16x8*)(A + (size_t)(m0 + r) * K + kb + cu * 8);
            bv[i] = *(const bf16x8*)(B + (size_t)(n0 + r) * K + kb + cu * 8);
        }
        __syncthreads();
#pragma unroll
        for (int i = 0; i < 2; ++i) {
            const int unit = i * 256 + t;
            const int r = unit >> 2, cu = unit & 3;
            *(bf16x8*)(Al + r * 32 + cu * 8) = av[i];
            *(bf16x8*)(Bl + r * 32 + cu * 8) = bv[i];
        }
        __syncthreads();

        bf16x8 af[4], bfr[4];
#pragma unroll
        for (int i = 0; i < 4; ++i)
            af[i] = *(const bf16x8*)(Al + (wy * 64 + i * 16 + lm) * 32 + quad * 8);
#pragma unroll
        for (int j = 0; j < 4; ++j)
            bfr[j] = *(const bf16x8*)(Bl + (wx * 64 + j * 16 + lm) * 32 + quad * 8);
#pragma unroll
        for (int i = 0; i < 4; ++i)
#pragma unroll
            for (int j = 0; j < 4; ++j)
                acc[i][j] = __builtin_amdgcn_mfma_f32_16x16x32_bf16(af[i], bfr[j], acc[i][j], 0, 0, 0);
    }

#pragma unroll
    for (int j = 0; j < 4; ++j) {
        const int n = n0 + wx * 64 + j * 16 + lm;
        const float bs = bias[n];
#pragma unroll
        for (int i = 0; i < 4; ++i) {
            const int mrow = m0 + wy * 64 + i * 16 + quad * 4;
#pragma unroll
            for (int rg = 0; rg < 4; ++rg) {
                const float val = acc[i][j][rg] + bs;
                if (OUT_BF16) ((u16*)Cout)[(size_t)(mrow + rg) * N + n] = f2bf(val);
                else          ((float*)Cout)[(size_t)(mrow + rg) * N + n] = val;
            }
        }
    }
}

// ---------------------------------------------------------------------------
// attn_v5 — v4 structure + q-tile 32 (512 thr) + XCD-local k-span swizzle.
//
// Grid = 512 blocks: combo = bid & 7 (-> XCD under %8 round-robin dispatch),
//   b = combo>>2, ks = combo&3 (KSPLIT=4 k-span of 512 keys), qt = bid>>3.
// Each XCD's L2 then only serves ONE (b,ks) combo: 1 MB K-span + 1 MB
// Vt-span -> resident in 4 MiB L2 (was L3-served in v4).
//
// Block: 8 waves. qs = w>>2 picks the 16-row q-sub-tile; wsub = w&3 is the
// 16-key slice (QK phase) or the 4-head group (PV phase). Both q-sub-tiles
// read the same K/Vt bytes -> L1/L2 reuse, traffic halved vs v4.
// Softmax over heads in registers (v4-verified). P via LDS (72.0 KB, one
// block/CU; epilogue reuses P as 64 KB staging).
// ---------------------------------------------------------------------------
#define PST 72   // Pb row stride (u16): 64 keys + 8 pad

__global__ __launch_bounds__(512, 2)
void attn_v5(const u16* __restrict__ Q, const u16* __restrict__ K,
             const u16* __restrict__ Vt,
             u16* __restrict__ c0, u16* __restrict__ c1,
             u16* __restrict__ c2, u16* __restrict__ c3)
{
    __shared__ u16 Pb[2 * NH * 16 * PST];    // [qs][h][q16][72] = 73728 B

    const int t     = threadIdx.x;
    const int w     = t >> 6, lane = t & 63;
    const int quad  = lane >> 4, lm = lane & 15;
    const int qs    = w >> 2;            // q-sub-tile 0/1
    const int wsub  = w & 3;             // key-slice (QK) / head-group (PV)
    const int combo = blockIdx.x & 7;
    const int b     = combo >> 2;
    const int ks    = combo & 3;
    const int qt    = blockIdx.x >> 3;   // 0..63
    const int q0    = qt * 32;
    const int kbeg  = ks * (S_LEN / 4);  // 512-key span

    const size_t qrow = ((size_t)b * S_LEN + q0 + qs * 16 + lm) * E_DIM;
    const size_t kmat = (size_t)b * S_LEN * E_DIM;
    const size_t vtb  = (size_t)b * E_DIM * S_LEN;

    f32x4 acc[4][4] = {};   // [h2][dtile] for heads wsub*4..wsub*4+3, q-sub qs

    for (int sc4 = 0; sc4 < (S_LEN / 4) / 64; ++sc4) {
        const int kloc = kbeg + sc4 * 64;          // superchunk base
        const int kw   = kloc + wsub * 16;         // this wave's key slice

        // ---- QK: all 16 heads, 16q x 16k, scores stay in registers ----
        f32x4 s[NH];
#pragma unroll
        for (int h = 0; h < NH; ++h) {
            const size_t qoff = qrow + h * 64 + quad * 8;
            const size_t koff = kmat + (size_t)(kw + lm) * E_DIM + h * 64 + quad * 8;
            bf16x8 qf0 = *(const bf16x8*)(Q + qoff);
            bf16x8 qf1 = *(const bf16x8*)(Q + qoff + 32);
            bf16x8 kf0 = *(const bf16x8*)(K + koff);
            bf16x8 kf1 = *(const bf16x8*)(K + koff + 32);
            f32x4 sf = {};
            sf = __builtin_amdgcn_mfma_f32_16x16x32_bf16(qf0, kf0, sf, 0, 0, 0);
            sf = __builtin_amdgcn_mfma_f32_16x16x32_bf16(qf1, kf1, sf, 0, 0, 0);
            s[h] = sf;
        }

        // ---- softmax over heads per (q,k) element, then P -> LDS ----
#pragma unroll
        for (int rg = 0; rg < 4; ++rg) {
            float M = s[0][rg];
#pragma unroll
            for (int h = 1; h < NH; ++h) M = fmaxf(M, s[h][rg]);
            float e[NH]; float Ssum = 0.f;
#pragma unroll
            for (int h = 0; h < NH; ++h) {
                e[h] = __expf((s[h][rg] - M) * 0.125f);   // 1/sqrt(64)
                Ssum += e[h];
            }
            const float inv = 1.f / Ssum;
            const int qq = quad * 4 + rg;
#pragma unroll
            for (int h = 0; h < NH; ++h)
                Pb[((qs * NH + h) * 16 + qq) * PST + wsub * 16 + lm] = f2bf(e[h] * inv);
        }
        __syncthreads();

        // ---- PV: q-sub qs, heads wsub*4..+3, 64-key superchunk ----
#pragma unroll
        for (int h2 = 0; h2 < 4; ++h2) {
            const int h = wsub * 4 + h2;
#pragma unroll
            for (int kk = 0; kk < 2; ++kk) {
                bf16x8 pf = *(const bf16x8*)(Pb + ((qs * NH + h) * 16 + lm) * PST
                                             + kk * 32 + quad * 8);
#pragma unroll
                for (int dt = 0; dt < 4; ++dt) {
                    bf16x8 vf = *(const bf16x8*)(Vt + vtb
                                 + (size_t)(h * 64 + dt * 16 + lm) * S_LEN
                                 + kloc + kk * 32 + quad * 8);
                    acc[h2][dt] = __builtin_amdgcn_mfma_f32_16x16x32_bf16(pf, vf, acc[h2][dt], 0, 0, 0);
                }
            }
        }
        __syncthreads();   // WAR: next superchunk's P writes
    }

    // ---- epilogue: stage 32q x 1024e tile in LDS (reuse Pb), then store ----
    u16* Ol = Pb;          // 64 KB <= 72 KB
#pragma unroll
    for (int h2 = 0; h2 < 4; ++h2) {
        const int h = wsub * 4 + h2;
#pragma unroll
        for (int dt = 0; dt < 4; ++dt)
#pragma unroll
            for (int rg = 0; rg < 4; ++rg)
                Ol[(qs * 16 + quad * 4 + rg) * 1024 + h * 64 + dt * 16 + lm]
                    = f2bf(acc[h2][dt][rg]);
    }
    __syncthreads();
    u16* dst = (ks == 0) ? c0 : (ks == 1) ? c1 : (ks == 2) ? c2 : c3;
#pragma unroll
    for (int i = 0; i < 8; ++i) {
        const int unit = i * 512 + t;
        const int r = unit >> 7, cu = unit & 127;   // r 0..31, cu 0..127
        *(bf16x8*)(dst + ((size_t)b * S_LEN + q0 + r) * E_DIM + cu * 8) =
            *(const bf16x8*)(Ol + r * 1024 + cu * 8);
    }
}

// ---------------------------------------------------------------------------
extern "C" void kernel_launch(void* const* d_in, const int* in_sizes, int n_in,
                              void* d_out, int out_size, void* d_ws, size_t ws_size,
                              hipStream_t stream)
{
    const float* x  = (const float*)d_in[0];
    const float* Wq = (const float*)d_in[1];
    const float* bq = (const float*)d_in[2];
    const float* Wk = (const float*)d_in[3];
    const float* bk = (const float*)d_in[4];
    const float* Wv = (const float*)d_in[5];
    const float* bv = (const float*)d_in[6];
    const float* Wo = (const float*)d_in[7];
    const float* bo = (const float*)d_in[8];
    float* out = (float*)d_out;

    // bf16 workspace (u16 elems), 72 MB total — identical layout to R4:
    const size_t MAT = (size_t)M_ROWS * E_DIM;   // 4M elems
    const size_t WSZ = (size_t)E_DIM * E_DIM;    // 1M elems
    u16* xb   = (u16*)d_ws;          // x; later combined ctx
    u16* Wqb  = xb   + MAT;
    u16* Wkb  = Wqb  + WSZ;
    u16* Wvb  = Wkb  + WSZ;
    u16* Wob  = Wvb  + WSZ;
    u16* Qb   = Wob  + WSZ;
    u16* Kb   = Qb   + MAT;
    u16* Vb   = Kb   + MAT;          // V; dead after transpose -> ctx partial 0
    u16* Vtb  = Vb   + MAT;
    u16* ctx1 = Vtb  + MAT;
    u16* ctx2 = ctx1 + MAT;
    u16* ctx3 = ctx2 + MAT;
    u16* ctx0 = Vb;

    // 1) convert inputs to bf16
    cvt_bf16<<<(int)(MAT / 1024), 256, 0, stream>>>(x,  xb,  (int)MAT);
    cvt_bf16<<<(int)(WSZ / 1024), 256, 0, stream>>>(Wq, Wqb, (int)WSZ);
    cvt_bf16<<<(int)(WSZ / 1024), 256, 0, stream>>>(Wk, Wkb, (int)WSZ);
    cvt_bf16<<<(int)(WSZ / 1024), 256, 0, stream>>>(Wv, Wvb, (int)WSZ);
    cvt_bf16<<<(int)(WSZ / 1024), 256, 0, stream>>>(Wo, Wob, (int)WSZ);

    // 2) Q/K/V projections (bf16 out)
    dim3 ggrid(M_ROWS / 128, E_DIM / 128);   // 32 x 8
    gemm_bt<true><<<ggrid, 256, 0, stream>>>(xb, Wqb, bq, Qb, M_ROWS, E_DIM, E_DIM);
    gemm_bt<true><<<ggrid, 256, 0, stream>>>(xb, Wkb, bk, Kb, M_ROWS, E_DIM, E_DIM);
    gemm_bt<true><<<ggrid, 256, 0, stream>>>(xb, Wvb, bv, Vb, M_ROWS, E_DIM, E_DIM);

    // 3) V transpose -> Vt [b][e][s]
    transpose_v<<<BATCH * 128, 256, 0, stream>>>(Vb, Vtb);

    // 4) fused MFMA attention, q-tile 32, XCD-local k-spans, KSPLIT=4
    attn_v5<<<512, 512, 0, stream>>>(Qb, Kb, Vtb, ctx0, ctx1, ctx2, ctx3);

    // 5) combine k-quarters into xb (x is dead)
    combine4<<<(int)(MAT / 1024), 256, 0, stream>>>(ctx0, ctx1, ctx2, ctx3, xb, (int)MAT);

    // 6) output projection (fp32 out)
    gemm_bt<false><<<ggrid, 256, 0, stream>>>(xb, Wob, bo, out, M_ROWS, E_DIM, E_DIM);
}

// Round 6
// 447.202 us; speedup vs baseline: 1.4354x; 1.4354x over previous
//
#include <hip/hip_runtime.h>
#include <cstddef>
#include <cstdint>

// Problem: B=2, S=2048, E=1024, H=16, D=64.  Softmax over HEADS (ref quirk).
#define BATCH 2
#define S_LEN 2048
#define E_DIM 1024
#define NH    16
#define HD    64
#define M_ROWS (BATCH * S_LEN)   // 4096

typedef unsigned short u16;
typedef short  bf16x8 __attribute__((ext_vector_type(8)));
typedef float  f32x4  __attribute__((ext_vector_type(4)));

__device__ __forceinline__ u16 f2bf(float f) {
    union { float f; unsigned u; } v; v.f = f;
    unsigned r = v.u + 0x7fffu + ((v.u >> 16) & 1u);   // RNE
    return (u16)(r >> 16);
}
__device__ __forceinline__ float bf2f(u16 h) {
    union { unsigned u; float f; } v; v.u = ((unsigned)h) << 16;
    return v.f;
}

// async global->LDS DMA, 16 B per lane (global_load_lds_dwordx4).
// lds base must be wave-uniform; HW writes lane i at base + i*16 B.
__device__ __forceinline__ void load_lds16(const u16* g, u16* l) {
    __builtin_amdgcn_global_load_lds(
        (const __attribute__((address_space(1))) unsigned int*)g,
        (__attribute__((address_space(3))) unsigned int*)l, 16, 0, 0);
}

// ---------------------------------------------------------------------------
// fp32 -> bf16 bulk convert (n % 4 == 0)
// ---------------------------------------------------------------------------
__global__ void cvt_bf16(const float* __restrict__ in, u16* __restrict__ out, int n)
{
    int i = (blockIdx.x * 256 + threadIdx.x) * 4;
    if (i + 3 < n) {
        float4 v = *(const float4*)(in + i);
        u16 o[4] = { f2bf(v.x), f2bf(v.y), f2bf(v.z), f2bf(v.w) };
        *(uint2*)(out + i) = *(const uint2*)o;
    }
}

// ---------------------------------------------------------------------------
// ctx = a + b  (bf16 in, fp32 add, bf16 out)
// ---------------------------------------------------------------------------
__global__ void combine_ctx(const u16* __restrict__ a, const u16* __restrict__ b,
                            u16* __restrict__ c, int n)
{
    int i = (blockIdx.x * 256 + threadIdx.x) * 4;
    if (i + 3 < n) {
        uint2 ua = *(const uint2*)(a + i);
        uint2 ub = *(const uint2*)(b + i);
        const u16* pa = (const u16*)&ua; const u16* pb = (const u16*)&ub;
        u16 o[4];
#pragma unroll
        for (int j = 0; j < 4; ++j) o[j] = f2bf(bf2f(pa[j]) + bf2f(pb[j]));
        *(uint2*)(c + i) = *(const uint2*)o;
    }
}

// ---------------------------------------------------------------------------
// Fused QKV projection GEMM (m97-style DMA staging).
// A [M=4096][K=1024] bf16, W3 [N=3072][K] bf16 (Wq|Wk|Wv rows).
// Per n-tile routing: seg 0 -> Qb, 1 -> Kb, 2 -> V written TRANSPOSED to
// Vt[b][e][s] (kills the separate transpose kernel).
// 128x128 tile, BK=32, 256 thr, global_load_lds width=16 staging
// (LDS tiles unpadded, contiguous in DMA lane order - required, m104/m108).
// ---------------------------------------------------------------------------
__global__ __launch_bounds__(256)
void gemm_qkv(const u16* __restrict__ A, const u16* __restrict__ W3,
              const float* __restrict__ bq, const float* __restrict__ bk,
              const float* __restrict__ bv,
              u16* __restrict__ Qb, u16* __restrict__ Kb, u16* __restrict__ Vtb)
{
    __shared__ u16 Al[128 * 32];
    __shared__ u16 Bl[128 * 32];
    const int K = E_DIM;
    const int t = threadIdx.x;
    const int w = t >> 6, lane = t & 63;
    const int quad = lane >> 4, lm = lane & 15;
    const int wy = w >> 1, wx = w & 1;
    const int m0 = blockIdx.x * 128, n0 = blockIdx.y * 128;
    const int lrow  = lane >> 2;         // 0..15 (DMA row within 16-row group)
    const int lcol8 = (lane & 3) * 8;    // u16 col offset (16 B granules)

    f32x4 acc[4][4] = {};

    for (int kb = 0; kb < K; kb += 32) {
        __syncthreads();   // previous iteration's ds_reads complete
#pragma unroll
        for (int i = 0; i < 2; ++i) {
            const int r0 = w * 32 + i * 16;
            load_lds16(A  + (size_t)(m0 + r0 + lrow) * K + kb + lcol8, &Al[r0 * 32]);
            load_lds16(W3 + (size_t)(n0 + r0 + lrow) * K + kb + lcol8, &Bl[r0 * 32]);
        }
        __syncthreads();   // compiler drains vmcnt(0) before s_barrier

        bf16x8 af[4], bfr[4];
#pragma unroll
        for (int i = 0; i < 4; ++i)
            af[i] = *(const bf16x8*)(Al + (wy * 64 + i * 16 + lm) * 32 + quad * 8);
#pragma unroll
        for (int j = 0; j < 4; ++j)
            bfr[j] = *(const bf16x8*)(Bl + (wx * 64 + j * 16 + lm) * 32 + quad * 8);
#pragma unroll
        for (int i = 0; i < 4; ++i)
#pragma unroll
            for (int j = 0; j < 4; ++j)
                acc[i][j] = __builtin_amdgcn_mfma_f32_16x16x32_bf16(af[i], bfr[j], acc[i][j], 0, 0, 0);
    }

    const int seg = n0 >> 10;            // 0=Q, 1=K, 2=V  (128 | 1024)
    const int nl0 = n0 & 1023;
    const float* bs = (seg == 0) ? bq : (seg == 1) ? bk : bv;

    if (seg < 2) {
        u16* dst = (seg == 0) ? Qb : Kb;
#pragma unroll
        for (int j = 0; j < 4; ++j) {
            const int n = nl0 + wx * 64 + j * 16 + lm;
            const float bias = bs[n];
#pragma unroll
            for (int i = 0; i < 4; ++i) {
                const int mrow = m0 + wy * 64 + i * 16 + quad * 4;
#pragma unroll
                for (int rg = 0; rg < 4; ++rg)
                    dst[(size_t)(mrow + rg) * E_DIM + n] = f2bf(acc[i][j][rg] + bias);
            }
        }
    } else {
        // V: write transposed -> Vt[b][e][s]; 4 consecutive s per uint2 store
#pragma unroll
        for (int j = 0; j < 4; ++j) {
            const int n = nl0 + wx * 64 + j * 16 + lm;
            const float bias = bs[n];
#pragma unroll
            for (int i = 0; i < 4; ++i) {
                const int mrow = m0 + wy * 64 + i * 16 + quad * 4;
                const int batch = mrow >> 11;
                const int sloc  = mrow & 2047;
                u16 o[4];
#pragma unroll
                for (int rg = 0; rg < 4; ++rg) o[rg] = f2bf(acc[i][j][rg] + bias);
                *(uint2*)&Vtb[(size_t)batch * E_DIM * S_LEN + (size_t)n * S_LEN + sloc]
                    = *(const uint2*)o;
            }
        }
    }
}

// ---------------------------------------------------------------------------
// Output projection GEMM, same DMA-staged loop, fp32 out.
// ---------------------------------------------------------------------------
__global__ __launch_bounds__(256)
void gemm_wo(const u16* __restrict__ A, const u16* __restrict__ B,
             const float* __restrict__ bias, float* __restrict__ C)
{
    __shared__ u16 Al[128 * 32];
    __shared__ u16 Bl[128 * 32];
    const int K = E_DIM, N = E_DIM;
    const int t = threadIdx.x;
    const int w = t >> 6, lane = t & 63;
    const int quad = lane >> 4, lm = lane & 15;
    const int wy = w >> 1, wx = w & 1;
    const int m0 = blockIdx.x * 128, n0 = blockIdx.y * 128;
    const int lrow  = lane >> 2;
    const int lcol8 = (lane & 3) * 8;

    f32x4 acc[4][4] = {};

    for (int kb = 0; kb < K; kb += 32) {
        __syncthreads();
#pragma unroll
        for (int i = 0; i < 2; ++i) {
            const int r0 = w * 32 + i * 16;
            load_lds16(A + (size_t)(m0 + r0 + lrow) * K + kb + lcol8, &Al[r0 * 32]);
            load_lds16(B + (size_t)(n0 + r0 + lrow) * K + kb + lcol8, &Bl[r0 * 32]);
        }
        __syncthreads();

        bf16x8 af[4], bfr[4];
#pragma unroll
        for (int i = 0; i < 4; ++i)
            af[i] = *(const bf16x8*)(Al + (wy * 64 + i * 16 + lm) * 32 + quad * 8);
#pragma unroll
        for (int j = 0; j < 4; ++j)
            bfr[j] = *(const bf16x8*)(Bl + (wx * 64 + j * 16 + lm) * 32 + quad * 8);
#pragma unroll
        for (int i = 0; i < 4; ++i)
#pragma unroll
            for (int j = 0; j < 4; ++j)
                acc[i][j] = __builtin_amdgcn_mfma_f32_16x16x32_bf16(af[i], bfr[j], acc[i][j], 0, 0, 0);
    }

#pragma unroll
    for (int j = 0; j < 4; ++j) {
        const int n = n0 + wx * 64 + j * 16 + lm;
        const float bs = bias[n];
#pragma unroll
        for (int i = 0; i < 4; ++i) {
            const int mrow = m0 + wy * 64 + i * 16 + quad * 4;
#pragma unroll
            for (int rg = 0; rg < 4; ++rg)
                C[(size_t)(mrow + rg) * N + n] = acc[i][j][rg] + bs;
        }
    }
}

// ---------------------------------------------------------------------------
// attn_v3 (verbatim from R3 — best measured attention: 296 us).
// MFMA attention, softmax over heads; wave owns 4 heads; KSPLIT=2.
// ---------------------------------------------------------------------------
__global__ __launch_bounds__(256, 2)
void attn_v3(const u16* __restrict__ Q, const u16* __restrict__ K,
             const u16* __restrict__ Vt, u16* __restrict__ ctxA,
             u16* __restrict__ ctxB)
{
    __shared__ float Sb[16 * 16 * 32];   // [h][q][k]
    __shared__ u16   Pb[16 * 16 * 32];   // [h][q][k]

    const int t     = threadIdx.x;
    const int w     = t >> 6, lane = t & 63;
    const int quad  = lane >> 4, lm = lane & 15;
    const int khalf = blockIdx.x & 1;
    const int qt    = (blockIdx.x >> 1) & 127;
    const int b     = blockIdx.x >> 8;
    const int q0    = qt * 16;

    const size_t qbase = ((size_t)b * S_LEN + q0) * E_DIM;
    const size_t kmat  = (size_t)b * S_LEN * E_DIM;
    const size_t vtb   = (size_t)b * E_DIM * S_LEN;

    bf16x8 qf[4][2];
#pragma unroll
    for (int h2 = 0; h2 < 4; ++h2)
#pragma unroll
        for (int hf = 0; hf < 2; ++hf)
            qf[h2][hf] = *(const bf16x8*)(Q + qbase + (size_t)lm * E_DIM
                                          + (w * 4 + h2) * 64 + hf * 32 + quad * 8);

    f32x4 acc[4][4] = {};   // [h2][dtile]

    const int kbeg = khalf * (S_LEN / 2);

    for (int c = 0; c < (S_LEN / 2) / 32; ++c) {
        const int k0 = kbeg + c * 32;

        // ---- QK^T: scores for this wave's 4 heads ----
#pragma unroll
        for (int h2 = 0; h2 < 4; ++h2) {
            const int h = w * 4 + h2;
#pragma unroll
            for (int kt2 = 0; kt2 < 2; ++kt2) {
                f32x4 sf = {};
#pragma unroll
                for (int hf = 0; hf < 2; ++hf) {
                    bf16x8 kf = *(const bf16x8*)(K + kmat
                                 + (size_t)(k0 + kt2 * 16 + lm) * E_DIM
                                 + h * 64 + hf * 32 + quad * 8);
                    sf = __builtin_amdgcn_mfma_f32_16x16x32_bf16(qf[h2][hf], kf, sf, 0, 0, 0);
                }
#pragma unroll
                for (int rg = 0; rg < 4; ++rg)
                    Sb[h * 512 + (quad * 4 + rg) * 32 + kt2 * 16 + lm] = sf[rg];
            }
        }
        __syncthreads();

        // ---- wide softmax over heads: 2 (q,k) pairs per thread ----
#pragma unroll
        for (int p = 0; p < 2; ++p) {
            const int idx = p * 256 + t;
            const int qq = idx >> 5, kk = idx & 31;
            float sv[16]; float mx = -1e30f;
#pragma unroll
            for (int h = 0; h < 16; ++h) {
                sv[h] = Sb[h * 512 + qq * 32 + kk];
                mx = fmaxf(mx, sv[h]);
            }
            float sum = 0.f;
#pragma unroll
            for (int h = 0; h < 16; ++h) {
                sv[h] = __expf((sv[h] - mx) * 0.125f);   // 1/sqrt(64) folded in
                sum += sv[h];
            }
            const float inv = 1.f / sum;
#pragma unroll
            for (int h = 0; h < 16; ++h)
                Pb[h * 512 + qq * 32 + kk] = f2bf(sv[h] * inv);
        }
        __syncthreads();

        // ---- PV: ctx[q][d] += P[q,keys] * Vt[d,keys] ----
#pragma unroll
        for (int h2 = 0; h2 < 4; ++h2) {
            const int h = w * 4 + h2;
            bf16x8 pf = *(const bf16x8*)(Pb + h * 512 + lm * 32 + quad * 8);
#pragma unroll
            for (int dt = 0; dt < 4; ++dt) {
                bf16x8 vf = *(const bf16x8*)(Vt + vtb
                             + (size_t)(h * 64 + dt * 16 + lm) * S_LEN
                             + k0 + quad * 8);
                acc[h2][dt] = __builtin_amdgcn_mfma_f32_16x16x32_bf16(pf, vf, acc[h2][dt], 0, 0, 0);
            }
        }
    }

    __syncthreads();
    u16* Ol = (u16*)Sb;     // [16 q][1024 e]
#pragma unroll
    for (int h2 = 0; h2 < 4; ++h2) {
        const int h = w * 4 + h2;
#pragma unroll
        for (int dt = 0; dt < 4; ++dt)
#pragma unroll
            for (int rg = 0; rg < 4; ++rg)
                Ol[(quad * 4 + rg) * 1024 + h * 64 + dt * 16 + lm] = f2bf(acc[h2][dt][rg]);
    }
    __syncthreads();
    u16* dst = khalf ? ctxB : ctxA;
#pragma unroll
    for (int i = 0; i < 8; ++i) {
        const int unit = i * 256 + t;
        const int r = unit >> 7, cu = unit & 127;
        *(bf16x8*)(dst + ((size_t)b * S_LEN + q0 + r) * E_DIM + cu * 8) =
            *(const bf16x8*)(Ol + r * 1024 + cu * 8);
    }
}

// ---------------------------------------------------------------------------
extern "C" void kernel_launch(void* const* d_in, const int* in_sizes, int n_in,
                              void* d_out, int out_size, void* d_ws, size_t ws_size,
                              hipStream_t stream)
{
    const float* x  = (const float*)d_in[0];
    const float* Wq = (const float*)d_in[1];
    const float* bq = (const float*)d_in[2];
    const float* Wk = (const float*)d_in[3];
    const float* bk = (const float*)d_in[4];
    const float* Wv = (const float*)d_in[5];
    const float* bv = (const float*)d_in[6];
    const float* Wo = (const float*)d_in[7];
    const float* bo = (const float*)d_in[8];
    float* out = (float*)d_out;

    // bf16 workspace (u16 elems), 56 MB:
    const size_t MAT = (size_t)M_ROWS * E_DIM;   // 4M elems
    const size_t WSZ = (size_t)E_DIM * E_DIM;    // 1M elems
    u16* xb   = (u16*)d_ws;          // x; later combined ctx
    u16* W3   = xb   + MAT;          // Wq|Wk|Wv concat [3072][1024]
    u16* Wob  = W3   + 3 * WSZ;
    u16* Qb   = Wob  + WSZ;
    u16* Kb   = Qb   + MAT;
    u16* Vtb  = Kb   + MAT;          // V transposed [b][e][s]
    u16* ctxA = Vtb  + MAT;
    u16* ctxB = ctxA + MAT;

    // 1) convert inputs to bf16 (weights into concat buffer)
    cvt_bf16<<<(int)(MAT / 1024), 256, 0, stream>>>(x,  xb, (int)MAT);
    cvt_bf16<<<(int)(WSZ / 1024), 256, 0, stream>>>(Wq, W3,           (int)WSZ);
    cvt_bf16<<<(int)(WSZ / 1024), 256, 0, stream>>>(Wk, W3 + WSZ,     (int)WSZ);
    cvt_bf16<<<(int)(WSZ / 1024), 256, 0, stream>>>(Wv, W3 + 2 * WSZ, (int)WSZ);
    cvt_bf16<<<(int)(WSZ / 1024), 256, 0, stream>>>(Wo, Wob,          (int)WSZ);

    // 2) fused QKV projection (writes Qb, Kb, Vtb-transposed)
    dim3 qkvgrid(M_ROWS / 128, 3 * E_DIM / 128);   // 32 x 24 = 768 blocks
    gemm_qkv<<<qkvgrid, 256, 0, stream>>>(xb, W3, bq, bk, bv, Qb, Kb, Vtb);

    // 3) fused MFMA attention (softmax over heads), KSPLIT=2
    attn_v3<<<BATCH * 128 * 2, 256, 0, stream>>>(Qb, Kb, Vtb, ctxA, ctxB);

    // 4) combine k-halves into xb (x is dead)
    combine_ctx<<<(int)(MAT / 1024), 256, 0, stream>>>(ctxA, ctxB, xb, (int)MAT);

    // 5) output projection (fp32 out)
    dim3 ogrid(M_ROWS / 128, E_DIM / 128);         // 32 x 8
    gemm_wo<<<ogrid, 256, 0, stream>>>(xb, Wob, bo, out);
}